// Round 2
// baseline (875.932 us; speedup 1.0000x reference)
//
#include <hip/hip_runtime.h>
#include <cstdint>
#include <cstddef>

// Better_Transformer fused: B=16384, IN=4096, P=8, D=512
// Block-diagonal => per-partition independence => single fused kernel:
//   block = (64-row slab, partition p)
//   phase0: x slab -> LDS bf16 (prescale *g1+nb1 fused)
//   phaseA: GEMM1 (A from LDS, B=W1^T direct from global/L2) -> act -> o1 bf16 back into same LDS
//   phaseB: GEMM2 (A from LDS, B=W2^T) -> act -> +x residual (fp32 re-read) -> fp32 out
// LDS: exactly 64KB, XOR-swizzled (16B chunk ^ (m&7)) for bank balance -> 2 blocks/CU.

#define B_ROWS 16384
#define IN_SZ  4096
#define P_PART 8
#define D_DIM  512

typedef unsigned short ushort_t;
typedef __attribute__((ext_vector_type(8))) short short8;   // 8 x bf16 bits
typedef __attribute__((ext_vector_type(4))) float f32x4;

__device__ inline unsigned short f2bf(float f) {
  union { float f; unsigned int u; } c; c.f = f;
  unsigned int u = c.u;
  return (unsigned short)((u + 0x7fffu + ((u >> 16) & 1u)) >> 16);  // RNE
}

// element offset into the 64x512 swizzled LDS tile for logical (m, k)
__device__ inline int sw_off(int m, int k) {
  int c = k >> 3;                       // 16B chunk index 0..63
  return (m << 9) | (((c ^ (m & 7)) << 3) | (k & 7));
}

// ---------------------------------------------------------------- weight prep
// Wt[p][n][k] = W[p][k][n], fp32 -> bf16. grid (8 ktile, 8 ntile, 16), block 256
__global__ __launch_bounds__(256) void wconv_kernel(const float* __restrict__ w1,
                                                    const float* __restrict__ w2,
                                                    ushort_t* __restrict__ wt1,
                                                    ushort_t* __restrict__ wt2) {
  __shared__ float tile[64][68];
  const int p = blockIdx.z & 7;
  const float*  src = (blockIdx.z < 8) ? w1 : w2;
  ushort_t*     dst = (blockIdx.z < 8) ? wt1 : wt2;
  const int k0 = blockIdx.x * 64;
  const int n0 = blockIdx.y * 64;
  const int t = threadIdx.x;

  const float* base = src + ((size_t)p * D_DIM + k0) * D_DIM + n0;
#pragma unroll
  for (int i = 0; i < 4; ++i) {
    int f = t + i * 256;
    int kr = f >> 4;
    int c4 = f & 15;
    float4 v = *(const float4*)(base + (size_t)kr * D_DIM + c4 * 4);
    *(float4*)(&tile[kr][c4 * 4]) = v;
  }
  __syncthreads();
  ushort_t* obase = dst + ((size_t)p * D_DIM + n0) * D_DIM + k0;
#pragma unroll
  for (int i = 0; i < 4; ++i) {
    int f = t + i * 256;
    int nr = f >> 4;
    int kc = (f & 15) * 4;
    unsigned int lo = f2bf(tile[kc + 0][nr]) | ((unsigned int)f2bf(tile[kc + 1][nr]) << 16);
    unsigned int hi = f2bf(tile[kc + 2][nr]) | ((unsigned int)f2bf(tile[kc + 3][nr]) << 16);
    uint2 pk; pk.x = lo; pk.y = hi;
    *(uint2*)(obase + (size_t)nr * D_DIM + kc) = pk;
  }
}

// ---------------------------------------------------------------- fused MLP
__device__ inline void gemm_k512(const ushort_t* __restrict__ xs,
                                 const ushort_t* __restrict__ wp,  // [n][k] bf16, n-base = wave chunk
                                 int l15, int quad, f32x4 acc[4][8]) {
  for (int kk = 0; kk < 16; ++kk) {
    const int k0 = kk * 32 + quad * 8;
    short8 a[4];
#pragma unroll
    for (int i = 0; i < 4; ++i)
      a[i] = *(const short8*)(&xs[sw_off(i * 16 + l15, k0)]);
#pragma unroll
    for (int jh = 0; jh < 2; ++jh) {
      short8 b[4];
#pragma unroll
      for (int j = 0; j < 4; ++j)
        b[j] = *(const short8*)(wp + (size_t)(jh * 64 + j * 16 + l15) * D_DIM + k0);
#pragma unroll
      for (int i = 0; i < 4; ++i)
#pragma unroll
        for (int j = 0; j < 4; ++j)
          acc[i][jh * 4 + j] =
              __builtin_amdgcn_mfma_f32_16x16x32_bf16(a[i], b[j], acc[i][jh * 4 + j], 0, 0, 0);
    }
  }
}

__global__ __launch_bounds__(256, 2) void fused_kernel(
    const float* __restrict__ x,
    const ushort_t* __restrict__ wt1, const ushort_t* __restrict__ wt2,
    const float* __restrict__ bias1, const float* __restrict__ gamma1,
    const float* __restrict__ beta1,
    const float* __restrict__ bias2, const float* __restrict__ gamma3,
    const float* __restrict__ beta3,
    const float* __restrict__ gain1, const float* __restrict__ nbias1,
    const float* __restrict__ gain3, const float* __restrict__ nbias3,
    float* __restrict__ out) {
  __shared__ __align__(16) ushort_t xs[64 * 512];   // 64KB, swizzled

  const int t = threadIdx.x;
  const int lane = t & 63, w = t >> 6;
  const int l15 = lane & 15, quad = lane >> 4;
  const int p = blockIdx.x;          // partition (XCD-aligned: dispatch id % 8 == p)
  const int m0 = blockIdx.y * 64;    // row slab

  const float g1 = gain1[0], nb1 = nbias1[0];
  const float g3 = gain3[0], nb3 = nbias3[0];

  // ---- phase 0: x slab -> bf16 LDS with prescale
  const float* xg = x + (size_t)m0 * IN_SZ + p * D_DIM;
#pragma unroll
  for (int i = 0; i < 32; ++i) {
    int f = t + i * 256;             // 0..8191 float4 slots
    int row = f >> 7, c4 = f & 127;  // c4: float4 index within row (0..127)
    float4 v = *(const float4*)(xg + (size_t)row * IN_SZ + c4 * 4);
    v.x = v.x * g1 + nb1; v.y = v.y * g1 + nb1;
    v.z = v.z * g1 + nb1; v.w = v.w * g1 + nb1;
    uint2 pk;
    pk.x = f2bf(v.x) | ((unsigned int)f2bf(v.y) << 16);
    pk.y = f2bf(v.z) | ((unsigned int)f2bf(v.w) << 16);
    *(uint2*)(&xs[sw_off(row, c4 * 4)]) = pk;
  }
  __syncthreads();

  // ---- phase A: o1 = swish1(xs @ W1_p + b1) * g3 + nb3
  f32x4 acc[4][8];
#pragma unroll
  for (int i = 0; i < 4; ++i)
#pragma unroll
    for (int j = 0; j < 8; ++j) acc[i][j] = (f32x4)(0.0f);

  const ushort_t* w1p = wt1 + (size_t)p * D_DIM * D_DIM + (size_t)(w * 128) * D_DIM;
  gemm_k512(xs, w1p, l15, quad, acc);

  __syncthreads();  // everyone done reading xs before o1 overwrites it

#pragma unroll
  for (int j = 0; j < 8; ++j) {
    int nloc = w * 128 + j * 16 + l15;
    int col = p * D_DIM + nloc;
    float bv = bias1[col], ga = gamma1[col], be = beta1[col];
#pragma unroll
    for (int i = 0; i < 4; ++i) {
#pragma unroll
      for (int r = 0; r < 4; ++r) {
        int m = i * 16 + quad * 4 + r;
        float v = acc[i][j][r] + bv;
        float sg = 1.0f / (1.0f + __expf(-be * v));
        float o = (ga + sg * (1.0f - ga)) * v;
        o = o * g3 + nb3;
        xs[sw_off(m, nloc)] = f2bf(o);
      }
    }
  }
  __syncthreads();

  // ---- phase B: out = swish2(o1 @ W2_p + b2) + x
#pragma unroll
  for (int i = 0; i < 4; ++i)
#pragma unroll
    for (int j = 0; j < 8; ++j) acc[i][j] = (f32x4)(0.0f);

  const ushort_t* w2p = wt2 + (size_t)p * D_DIM * D_DIM + (size_t)(w * 128) * D_DIM;
  gemm_k512(xs, w2p, l15, quad, acc);

#pragma unroll
  for (int j = 0; j < 8; ++j) {
    int col = p * D_DIM + w * 128 + j * 16 + l15;
    float bv = bias2[col], ga = gamma3[col], be = beta3[col];
#pragma unroll
    for (int i = 0; i < 4; ++i) {
#pragma unroll
      for (int r = 0; r < 4; ++r) {
        int row = m0 + i * 16 + quad * 4 + r;
        float v = acc[i][j][r] + bv;
        float sg = 1.0f / (1.0f + __expf(-be * v));
        float o = (ga + sg * (1.0f - ga)) * v;
        size_t idx = (size_t)row * IN_SZ + col;
        out[idx] = o + x[idx];
      }
    }
  }
}

// ---------------------------------------------------------------- launch
extern "C" void kernel_launch(void* const* d_in, const int* in_sizes, int n_in,
                              void* d_out, int out_size, void* d_ws, size_t ws_size,
                              hipStream_t stream) {
  const float* x      = (const float*)d_in[0];
  const float* w1     = (const float*)d_in[1];
  const float* b1     = (const float*)d_in[2];
  const float* w2     = (const float*)d_in[3];
  const float* b2     = (const float*)d_in[4];
  const float* gamma1 = (const float*)d_in[5];
  const float* beta1  = (const float*)d_in[6];
  const float* gamma3 = (const float*)d_in[7];
  const float* beta3  = (const float*)d_in[8];
  const float* gain1  = (const float*)d_in[9];
  const float* nbias1 = (const float*)d_in[10];
  const float* gain3  = (const float*)d_in[11];
  const float* nbias3 = (const float*)d_in[12];
  float* out = (float*)d_out;

  // ws: Wt1 bf16 (4MB) | Wt2 bf16 (4MB)
  ushort_t* wt1 = (ushort_t*)d_ws;
  ushort_t* wt2 = wt1 + (size_t)P_PART * D_DIM * D_DIM;

  wconv_kernel<<<dim3(8, 8, 16), 256, 0, stream>>>(w1, w2, wt1, wt2);
  fused_kernel<<<dim3(P_PART, B_ROWS / 64), 256, 0, stream>>>(
      x, wt1, wt2, b1, gamma1, beta1, b2, gamma3, beta3,
      gain1, nbias1, gain3, nbias3, out);
}